// Round 7
// baseline (309.730 us; speedup 1.0000x reference)
//
#include <hip/hip_runtime.h>
#include <stdint.h>

constexpr int S = 1024;
constexpr int D = 1024;
constexpr int NB = 8;

typedef __bf16 bf16x8 __attribute__((ext_vector_type(8)));
typedef float floatx4 __attribute__((ext_vector_type(4)));

#define AS1 __attribute__((address_space(1)))
#define AS3 __attribute__((address_space(3)))

__device__ __forceinline__ unsigned short f2bf(float f) {
  unsigned u = __builtin_bit_cast(unsigned, f);
  u += 0x7fffu + ((u >> 16) & 1u);  // RNE
  return (unsigned short)(u >> 16);
}

__device__ __forceinline__ float bf2f(unsigned short x) {
  unsigned u = ((unsigned)x) << 16;
  return __builtin_bit_cast(float, u);
}

__device__ __forceinline__ void gload16(const void* g, void* l) {
  __builtin_amdgcn_global_load_lds((const AS1 unsigned int*)g, (AS3 unsigned int*)l, 16, 0, 0);
}

// ---------------- prep: casts + Wv transpose + bias vectors u,v,c ----------------
// Algebra: scores = hs·(Wq Wk^T/8)·rhs^T + t2 + t3 (head-sum before softmax makes the
// score a FULL-D dot product -> the K-projection is algebraically redundant).
__global__ __launch_bounds__(256) void prep_kernel(
    const float4* __restrict__ hs4, const float4* __restrict__ rhs4,
    ushort4* __restrict__ hsb4, ushort4* __restrict__ rhsb4, int n4,
    const float* __restrict__ Wq, const float* __restrict__ Wk, const float* __restrict__ Wv,
    unsigned short* __restrict__ WvT, ushort4* __restrict__ Wqb4, ushort4* __restrict__ Wkb4,
    const float* __restrict__ bq, const float* __restrict__ bk, float* __restrict__ u,
    float* __restrict__ v, float* __restrict__ cbuf) {
  __shared__ float tile[32][33];
  const int bid = blockIdx.x;
  if (bid < 16384) {  // cast hs, rhs -> bf16
    int i = bid * 256 + threadIdx.x;
    const float4* src;
    ushort4* dst;
    int j;
    if (i < n4) {
      src = hs4; dst = hsb4; j = i;
    } else {
      src = rhs4; dst = rhsb4; j = i - n4;
    }
    float4 w = src[j];
    ushort4 o;
    o.x = f2bf(w.x); o.y = f2bf(w.y); o.z = f2bf(w.z); o.w = f2bf(w.w);
    dst[j] = o;
  } else if (bid < 18432) {  // straight casts Wq->Wqb, Wk->Wkb (no transpose needed)
    int j = (bid - 16384) * 256 + threadIdx.x;  // 0..524287
    const float4* src = (j < 262144) ? (const float4*)Wq : (const float4*)Wk;
    ushort4* dst = (j < 262144) ? Wqb4 : Wkb4;
    int jj = (j < 262144) ? j : j - 262144;
    float4 w = src[jj];
    ushort4 o;
    o.x = f2bf(w.x); o.y = f2bf(w.y); o.z = f2bf(w.z); o.w = f2bf(w.w);
    dst[jj] = o;
  } else if (bid < 19456) {  // transpose-cast Wv -> WvT
    const int r = bid - 18432;     // 0..1023
    const int bx = (r & 31) * 32;  // n block
    const int by = (r >> 5) * 32;  // k block
    const int x = threadIdx.x & 31;
    const int y0 = threadIdx.x >> 5;
    for (int i = 0; i < 4; ++i) {
      int y = y0 + i * 8;
      tile[y][x] = Wv[(by + y) * D + bx + x];
    }
    __syncthreads();
    for (int i = 0; i < 4; ++i) {
      int y = y0 + i * 8;
      WvT[(long long)(bx + y) * D + by + x] = f2bf(tile[x][y]);
    }
  } else if (bid < 19460) {  // u = Wq @ bk / 8
    const int d = (bid - 19456) * 256 + threadIdx.x;
    const float* row = Wq + (long long)d * 1024;
    float s = 0.f;
    for (int c = 0; c < 1024; ++c) s += row[c] * bk[c];
    u[d] = 0.125f * s;
  } else if (bid < 19464) {  // v = Wk @ bq / 8
    const int d = (bid - 19460) * 256 + threadIdx.x;
    const float* row = Wk + (long long)d * 1024;
    float s = 0.f;
    for (int c = 0; c < 1024; ++c) s += row[c] * bq[c];
    v[d] = 0.125f * s;
  } else {  // c = bq·bk / 8
    __shared__ float sh[256];
    const int tid = threadIdx.x;
    float s = 0.f;
    for (int c = tid; c < 1024; c += 256) s += bq[c] * bk[c];
    sh[tid] = s;
    __syncthreads();
    for (int o = 128; o; o >>= 1) {
      if (tid < o) sh[tid] += sh[tid + o];
      __syncthreads();
    }
    if (tid == 0) cbuf[0] = 0.125f * sh[0];
  }
}

// ====== GEMM core (R0-proven loop): 128x128 tile, BK=32, global_load_lds, 2 barriers ======
// Source-chunk XOR swizzle: lane (row, c) loads global chunk c^((row>>1)&3) into LDS chunk c.
// Reader: physical chunk = quad ^ ((r15>>1)&3) -> XOR cancels -> conflict-free.

#define GEMM_STAGE_SETUP(Abase, lda_, Bbase, ldb_)                            \
  const int srow = tid >> 2;                                                  \
  const int scg = (((tid & 3) ^ ((srow >> 1) & 3)) * 8);                      \
  const unsigned short* aG0 = (Abase) + (long long)srow * (lda_) + scg;       \
  const unsigned short* aG1 = aG0 + (long long)64 * (lda_);                   \
  const unsigned short* bG0 = (Bbase) + (long long)srow * (ldb_) + scg;       \
  const unsigned short* bG1 = bG0 + (long long)64 * (ldb_);                   \
  unsigned short* aL0 = As + w * 512;                                         \
  unsigned short* aL1 = As + w * 512 + 2048;                                  \
  unsigned short* bL0 = Bs + w * 512;                                         \
  unsigned short* bL1 = Bs + w * 512 + 2048;

#define GEMM_KLOOP(Klen)                                                               \
  for (int k0 = 0; k0 < (Klen); k0 += 32) {                                            \
    gload16(aG0 + k0, aL0);                                                            \
    gload16(aG1 + k0, aL1);                                                            \
    gload16(bG0 + k0, bL0);                                                            \
    gload16(bG1 + k0, bL1);                                                            \
    __syncthreads();                                                                   \
    bf16x8 af[4], bfr[4];                                                              \
    for (int t = 0; t < 4; ++t) {                                                      \
      af[t] = *reinterpret_cast<const bf16x8*>(As + (wm + t * 16 + r15) * 32 + pq);    \
      bfr[t] = *reinterpret_cast<const bf16x8*>(Bs + (wn + t * 16 + r15) * 32 + pq);   \
    }                                                                                  \
    for (int mt = 0; mt < 4; ++mt)                                                     \
      for (int nt = 0; nt < 4; ++nt)                                                   \
        acc[mt][nt] =                                                                  \
            __builtin_amdgcn_mfma_f32_16x16x32_bf16(af[mt], bfr[nt], acc[mt][nt], 0, 0, 0); \
    __syncthreads();                                                                   \
  }

#define GEMM_COMMON_IDX                  \
  const int tid = threadIdx.x;           \
  const int lane = tid & 63;             \
  const int w = tid >> 6;                \
  const int r15 = lane & 15;             \
  const int quad = lane >> 4;            \
  const int pq = (quad ^ ((r15 >> 1) & 3)) * 8; \
  const int wm = (w >> 1) * 64;          \
  const int wn = (w & 1) * 64;

#define GEMM_ACC_INIT                    \
  floatx4 acc[4][4];                     \
  for (int i = 0; i < 4; ++i)            \
    for (int j = 0; j < 4; ++j) acc[i][j] = {0.f, 0.f, 0.f, 0.f};

// ------- wprod: Mt[b,a] = sum_c Wk[b,c]Wq[a,c] /8, K-split x4 into fp32 partials -------
// Blocks 0..255: GEMM (8x8 tiles x 4 k-chunks of 256). Blocks 256..319: t2/t3 bias rows
// (t2[i] = hsb_i·u + c/2, t3[j] = rhsb_j·v + c/2) with all-zero-u early exit.
__global__ __launch_bounds__(256) void wprod_kernel(
    const unsigned short* __restrict__ Wkb, const unsigned short* __restrict__ Wqb,
    float* __restrict__ Mtf, const unsigned short* __restrict__ hsb,
    const unsigned short* __restrict__ rhsb, const float* __restrict__ u,
    const float* __restrict__ v, const float* __restrict__ cbuf, float* __restrict__ t2,
    float* __restrict__ t3) {
  __shared__ __align__(16) unsigned short As[128 * 32];
  __shared__ __align__(16) unsigned short Bs[128 * 32];
  const int bid = blockIdx.x;
  if (bid < 256) {
    GEMM_COMMON_IDX
    const int tilei = bid & 63;
    const int kc = bid >> 6;  // k-chunk 0..3
    const int bx = tilei & 7;
    const int by = tilei >> 3;
    const unsigned short* A = Wkb + (long long)by * 128 * D + kc * 256;
    const unsigned short* Bt = Wqb + (long long)bx * 128 * D + kc * 256;
    GEMM_STAGE_SETUP(A, D, Bt, D)
    GEMM_ACC_INIT
    GEMM_KLOOP(256)
    float* dst = Mtf + ((long long)kc << 20);
    for (int mt = 0; mt < 4; ++mt)
      for (int nt = 0; nt < 4; ++nt) {
        const int mrow = by * 128 + wm + mt * 16 + quad * 4;
        const int nc = bx * 128 + wn + nt * 16 + r15;
        floatx4 vv = acc[mt][nt];
        for (int e = 0; e < 4; ++e) dst[(long long)(mrow + e) * 1024 + nc] = vv[e] * 0.125f;
      }
  } else {
    const int tid = threadIdx.x;
    const bool isT2 = bid < 288;
    const int row = (isT2 ? (bid - 256) : (bid - 288)) * 256 + tid;  // 0..8191
    const float* vec = isT2 ? u : v;
    const unsigned short* mat = isT2 ? hsb : rhsb;
    float* out = isT2 ? t2 : t3;
    __shared__ int nz;
    if (tid == 0) nz = 0;
    __syncthreads();
    const float4* u4 = (const float4*)vec;
    float4 uu = u4[tid];
    if (uu.x != 0.f || uu.y != 0.f || uu.z != 0.f || uu.w != 0.f) nz = 1;
    __syncthreads();
    const float c2 = 0.5f * cbuf[0];
    if (!nz) {
      out[row] = c2;
      return;
    }
    const ushort4* r4 = (const ushort4*)(mat + (long long)row * 1024);
    float s = 0.f;
    for (int c4 = 0; c4 < 256; ++c4) {
      ushort4 h = r4[c4];
      s += bf2f(h.x) * vec[c4 * 4 + 0] + bf2f(h.y) * vec[c4 * 4 + 1] +
           bf2f(h.z) * vec[c4 * 4 + 2] + bf2f(h.w) * vec[c4 * 4 + 3];
    }
    out[row] = s + c2;
  }
}

// ------- castM: Mtb = bf16(sum of 4 fp32 K-partials) -------
__global__ __launch_bounds__(256) void castM_kernel(const float4* __restrict__ Mtf4,
                                                    ushort4* __restrict__ Mtb4) {
  const int j = blockIdx.x * 256 + threadIdx.x;  // 0..262143
  float4 a = Mtf4[j];
  float4 b = Mtf4[j + 262144];
  float4 c = Mtf4[j + 524288];
  float4 d = Mtf4[j + 786432];
  ushort4 o;
  o.x = f2bf(a.x + b.x + c.x + d.x);
  o.y = f2bf(a.y + b.y + c.y + d.y);
  o.z = f2bf(a.z + b.z + c.z + d.z);
  o.w = f2bf(a.w + b.w + c.w + d.w);
  Mtb4[j] = o;
}

// ---------------- fused GEMM: M=8192, N=2048: seg0 hsM = hsb·Mt^T, seg1 V-proj ----------------
__global__ __launch_bounds__(256) void gemm_fused_kernel(
    const unsigned short* __restrict__ hsb, const unsigned short* __restrict__ rhsb,
    const unsigned short* __restrict__ Mtb, const unsigned short* __restrict__ WvT,
    const float* __restrict__ bv, unsigned short* __restrict__ hsMb,
    unsigned short* __restrict__ Vmt) {
  __shared__ __align__(16) unsigned short As[128 * 32];
  __shared__ __align__(16) unsigned short Bs[128 * 32];
  GEMM_COMMON_IDX
  const int seg = (int)(blockIdx.x >> 3);         // 0=hsM 1=V
  const long long nloc = (blockIdx.x & 7) * 128;  // 0..1023
  const long long m0 = (long long)blockIdx.y * 128;
  const unsigned short* A = ((seg == 0) ? hsb : rhsb) + m0 * D;
  const unsigned short* Bt = ((seg == 0) ? Mtb : WvT) + nloc * D;

  GEMM_STAGE_SETUP(A, D, Bt, D)
  GEMM_ACC_INIT
  GEMM_KLOOP(D)

  for (int mt = 0; mt < 4; ++mt) {
    for (int nt = 0; nt < 4; ++nt) {
      const long long mrow = m0 + wm + mt * 16 + quad * 4;
      const long long nc = nloc + wn + nt * 16 + r15;
      floatx4 vv = acc[mt][nt];
      if (seg == 0) {
        for (int e = 0; e < 4; ++e) hsMb[(mrow + e) * D + nc] = f2bf(vv[e]);
      } else {
        const float bval = bv[nc];
        for (int e = 0; e < 4; ++e) {
          long long m = mrow + e;
          Vmt[(m >> 10) * (long long)(S * D) + nc * S + (m & 1023)] = f2bf(vv[e] + bval);
        }
      }
    }
  }
}

// ------- scores GEMM + fused mask/exp + partial row sums ---------
// sc = hsM·rhs (scale folded into Mt) + t2[row] + t3[col] + (1-mask)*-1e9; E = exp(sc).
// Batch-per-XCD swizzle: z = bid&7 (Qm/Km-free: A=hsM slice, B=rhsb slice, each 2MB).
__global__ __launch_bounds__(256) void gemm_scores_kernel(
    const unsigned short* __restrict__ hsMb, const unsigned short* __restrict__ rhsb,
    const float* __restrict__ mask, unsigned short* __restrict__ E, float* __restrict__ rowsumP,
    const float* __restrict__ t2, const float* __restrict__ t3) {
  __shared__ __align__(16) unsigned short As[128 * 32];
  __shared__ __align__(16) unsigned short Bs[128 * 32];
  GEMM_COMMON_IDX
  const int bid = blockIdx.x;  // 0..511
  const int z = bid & 7;       // batch == XCD
  const int r = bid >> 3;      // 0..63
  const int by = r >> 3;
  const int bx = r & 7;
  const long long m0 = (long long)by * 128;
  const long long n0 = (long long)bx * 128;
  const unsigned short* A = hsMb + (long long)z * S * D + m0 * D;
  const unsigned short* Bt = rhsb + (long long)z * S * D + n0 * D;

  GEMM_STAGE_SETUP(A, D, Bt, D)
  GEMM_ACC_INIT
  GEMM_KLOOP(D)

  const long long zE = (long long)z * S * 1024;
  float rowpart[4][4];
  for (int mt = 0; mt < 4; ++mt)
    for (int e = 0; e < 4; ++e) rowpart[mt][e] = 0.f;

  for (int mt = 0; mt < 4; ++mt) {
    for (int nt = 0; nt < 4; ++nt) {
      const long long mrow = m0 + wm + mt * 16 + quad * 4;
      const long long nc = n0 + wn + nt * 16 + r15;
      const float t3v = t3[z * 1024 + nc];
      floatx4 vv = acc[mt][nt];
      for (int e = 0; e < 4; ++e) {
        long long m = mrow + e;
        float mval = mask[zE + m * 1024 + nc];
        float sc = vv[e] + t2[z * 1024 + m] + t3v + (1.0f - mval) * -1e9f;
        float Ev = __expf(sc);
        E[zE + m * 1024 + nc] = f2bf(Ev);
        rowpart[mt][e] += Ev;
      }
    }
  }
  const int slot = (bx << 11) + ((wn >> 6) << 10);  // [ntile][half]
  for (int mt = 0; mt < 4; ++mt) {
    for (int e = 0; e < 4; ++e) {
      float s = rowpart[mt][e];
      s += __shfl_xor(s, 1, 64);
      s += __shfl_xor(s, 2, 64);
      s += __shfl_xor(s, 4, 64);
      s += __shfl_xor(s, 8, 64);
      if (r15 == 0) {
        int mloc = (int)(m0 + wm + mt * 16 + quad * 4 + e);
        rowsumP[(z << 14) + slot + mloc] = s;
      }
    }
  }
}

// ------- ctx GEMM: out = (E . Vmt^T) / rowsum, permuted store ---------
__global__ __launch_bounds__(256) void gemm_ctx_kernel(const unsigned short* __restrict__ E,
                                                       const unsigned short* __restrict__ Vmt,
                                                       const float* __restrict__ rowsumP,
                                                       float* __restrict__ out) {
  __shared__ __align__(16) unsigned short As[128 * 32];
  __shared__ __align__(16) unsigned short Bs[128 * 32];
  __shared__ float rsinv[128];
  GEMM_COMMON_IDX
  const int bid = blockIdx.x;  // 0..511
  const int z = bid & 7;
  const int r = bid >> 3;
  const int by = r >> 3;
  const int bx = r & 7;
  const long long m0 = (long long)by * 128;
  const long long n0 = (long long)bx * 128;
  const unsigned short* A = E + (long long)z * S * 1024 + m0 * 1024;
  const unsigned short* Bt = Vmt + (long long)z * S * D + n0 * D;

  if (tid < 128) {
    float s = 0.f;
    for (int t = 0; t < 16; ++t) s += rowsumP[(z << 14) + (t << 10) + (int)m0 + tid];
    rsinv[tid] = 1.0f / s;
  }

  GEMM_STAGE_SETUP(A, 1024, Bt, D)
  GEMM_ACC_INIT
  GEMM_KLOOP(1024)

  for (int mt = 0; mt < 4; ++mt) {
    for (int nt = 0; nt < 4; ++nt) {
      const int r0 = wm + mt * 16 + quad * 4;
      const long long ncol = n0 + wn + nt * 16 + r15;
      floatx4 vv = acc[mt][nt];
      for (int e = 0; e < 4; ++e) {
        long long m = m0 + r0 + e;
        float val = vv[e] * rsinv[r0 + e];
        out[(long long)z * S * D + (ncol >> 6) * (long long)(S * 64) + m * 64 + (ncol & 63)] =
            val;
      }
    }
  }
}

extern "C" void kernel_launch(void* const* d_in, const int* in_sizes, int n_in, void* d_out,
                              int out_size, void* d_ws, size_t ws_size, hipStream_t stream) {
  const float* hs = (const float*)d_in[0];
  const float* rhs = (const float*)d_in[1];
  const float* mask = (const float*)d_in[2];
  const float* Wq = (const float*)d_in[3];
  const float* bq = (const float*)d_in[4];
  const float* Wk = (const float*)d_in[5];
  const float* bk = (const float*)d_in[6];
  const float* Wv = (const float*)d_in[7];
  const float* bv = (const float*)d_in[8];
  float* out = (float*)d_out;
  char* ws = (char*)d_ws;
  const size_t MB = 1ull << 20;
  // layout (73 MB):
  // 0: WvT(2) | 2: Wqb(2) | 4: Wkb(2) | 6: Mtb(2) | 8: u/v/c/t2/t3/rowsumP (<1)
  // 9: hsb(16)  [E overlays after fused] | 25: rhsb(16)
  // 41: hsMb(16) [Mtf fp32 overlays BEFORE fused] | 57: Vmt(16)
  unsigned short* WvT = (unsigned short*)(ws + 0 * MB);
  unsigned short* Wqb = (unsigned short*)(ws + 2 * MB);
  unsigned short* Wkb = (unsigned short*)(ws + 4 * MB);
  unsigned short* Mtb = (unsigned short*)(ws + 6 * MB);
  float* u = (float*)(ws + 8 * MB);
  float* v = (float*)(ws + 8 * MB + 4096);
  float* cbuf = (float*)(ws + 8 * MB + 8192);
  float* t2 = (float*)(ws + 8 * MB + 16384);
  float* t3 = (float*)(ws + 8 * MB + 49152);
  float* rowsumP = (float*)(ws + 8 * MB + 131072);
  unsigned short* hsb = (unsigned short*)(ws + 9 * MB);
  unsigned short* rhsb = (unsigned short*)(ws + 25 * MB);
  unsigned short* hsMb = (unsigned short*)(ws + 41 * MB);
  float* Mtf = (float*)(ws + 41 * MB);
  unsigned short* Vmt = (unsigned short*)(ws + 57 * MB);
  unsigned short* E = (unsigned short*)(ws + 9 * MB);

  const int n4 = NB * S * D / 4;  // 2M float4 per input
  prep_kernel<<<19465, 256, 0, stream>>>((const float4*)hs, (const float4*)rhs, (ushort4*)hsb,
                                         (ushort4*)rhsb, n4, Wq, Wk, Wv, WvT, (ushort4*)Wqb,
                                         (ushort4*)Wkb, bq, bk, u, v, cbuf);

  // Mt = Wk·Wq^T/8 (K-split x4 into fp32 partials) + t2/t3 bias rows
  wprod_kernel<<<320, 256, 0, stream>>>(Wkb, Wqb, Mtf, hsb, rhsb, u, v, cbuf, t2, t3);
  castM_kernel<<<1024, 256, 0, stream>>>((const float4*)Mtf, (ushort4*)Mtb);

  // fused: hsM projection (replaces Q-proj + K-proj) | V projection
  gemm_fused_kernel<<<dim3(16, 64), 256, 0, stream>>>(hsb, rhsb, Mtb, WvT, bv, hsMb, Vmt);

  // E[b] = exp(hsM[b]·rhs[b]^T + t2 + t3 + mask) + partial row sums
  gemm_scores_kernel<<<512, 256, 0, stream>>>(hsMb, rhsb, mask, E, rowsumP, t2, t3);

  // ctx[b] = (E[b]·Vmt[b]^T)/rowsum, permuted fp32 store
  gemm_ctx_kernel<<<512, 256, 0, stream>>>(E, Vmt, rowsumP, out);
}

// Round 8
// 293.525 us; speedup vs baseline: 1.0552x; 1.0552x over previous
//
#include <hip/hip_runtime.h>
#include <stdint.h>

constexpr int S = 1024;
constexpr int D = 1024;
constexpr int NB = 8;

typedef __bf16 bf16x8 __attribute__((ext_vector_type(8)));
typedef float floatx4 __attribute__((ext_vector_type(4)));

#define AS1 __attribute__((address_space(1)))
#define AS3 __attribute__((address_space(3)))

__device__ __forceinline__ unsigned short f2bf(float f) {
  unsigned u = __builtin_bit_cast(unsigned, f);
  u += 0x7fffu + ((u >> 16) & 1u);  // RNE
  return (unsigned short)(u >> 16);
}

__device__ __forceinline__ float bf2f(unsigned short x) {
  unsigned u = ((unsigned)x) << 16;
  return __builtin_bit_cast(float, u);
}

__device__ __forceinline__ void gload16(const void* g, void* l) {
  __builtin_amdgcn_global_load_lds((const AS1 unsigned int*)g, (AS3 unsigned int*)l, 16, 0, 0);
}

// ---------------- prep: casts + Wv transpose + bias vectors u,v,c ----------------
// Algebra: scores = hs·(Wq Wk^T/8)·rhs^T + t2 + t3 (head-sum before softmax makes the
// score a FULL-D dot product -> the K-projection is algebraically redundant).
__global__ __launch_bounds__(256) void prep_kernel(
    const float4* __restrict__ hs4, const float4* __restrict__ rhs4,
    ushort4* __restrict__ hsb4, ushort4* __restrict__ rhsb4, int n4,
    const float* __restrict__ Wq, const float* __restrict__ Wk, const float* __restrict__ Wv,
    unsigned short* __restrict__ WvT, ushort4* __restrict__ Wqb4, ushort4* __restrict__ Wkb4,
    const float* __restrict__ bq, const float* __restrict__ bk, float* __restrict__ u,
    float* __restrict__ v, float* __restrict__ cbuf) {
  __shared__ float tile[32][33];
  const int bid = blockIdx.x;
  if (bid < 16384) {  // cast hs, rhs -> bf16
    int i = bid * 256 + threadIdx.x;
    const float4* src;
    ushort4* dst;
    int j;
    if (i < n4) {
      src = hs4; dst = hsb4; j = i;
    } else {
      src = rhs4; dst = rhsb4; j = i - n4;
    }
    float4 w = src[j];
    ushort4 o;
    o.x = f2bf(w.x); o.y = f2bf(w.y); o.z = f2bf(w.z); o.w = f2bf(w.w);
    dst[j] = o;
  } else if (bid < 18432) {  // straight casts Wq->Wqb, Wk->Wkb
    int j = (bid - 16384) * 256 + threadIdx.x;  // 0..524287
    const float4* src = (j < 262144) ? (const float4*)Wq : (const float4*)Wk;
    ushort4* dst = (j < 262144) ? Wqb4 : Wkb4;
    int jj = (j < 262144) ? j : j - 262144;
    float4 w = src[jj];
    ushort4 o;
    o.x = f2bf(w.x); o.y = f2bf(w.y); o.z = f2bf(w.z); o.w = f2bf(w.w);
    dst[jj] = o;
  } else if (bid < 19456) {  // transpose-cast Wv -> WvT
    const int r = bid - 18432;     // 0..1023
    const int bx = (r & 31) * 32;  // n block
    const int by = (r >> 5) * 32;  // k block
    const int x = threadIdx.x & 31;
    const int y0 = threadIdx.x >> 5;
    for (int i = 0; i < 4; ++i) {
      int y = y0 + i * 8;
      tile[y][x] = Wv[(by + y) * D + bx + x];
    }
    __syncthreads();
    for (int i = 0; i < 4; ++i) {
      int y = y0 + i * 8;
      WvT[(long long)(bx + y) * D + by + x] = f2bf(tile[x][y]);
    }
  } else if (bid < 19460) {  // u = Wq @ bk / 8
    const int d = (bid - 19456) * 256 + threadIdx.x;
    const float* row = Wq + (long long)d * 1024;
    float s = 0.f;
    for (int c = 0; c < 1024; ++c) s += row[c] * bk[c];
    u[d] = 0.125f * s;
  } else if (bid < 19464) {  // v = Wk @ bq / 8
    const int d = (bid - 19460) * 256 + threadIdx.x;
    const float* row = Wk + (long long)d * 1024;
    float s = 0.f;
    for (int c = 0; c < 1024; ++c) s += row[c] * bq[c];
    v[d] = 0.125f * s;
  } else {  // c = bq·bk / 8
    __shared__ float sh[256];
    const int tid = threadIdx.x;
    float s = 0.f;
    for (int c = tid; c < 1024; c += 256) s += bq[c] * bk[c];
    sh[tid] = s;
    __syncthreads();
    for (int o = 128; o; o >>= 1) {
      if (tid < o) sh[tid] += sh[tid + o];
      __syncthreads();
    }
    if (tid == 0) cbuf[0] = 0.125f * sh[0];
  }
}

// ====== GEMM cores. Source-chunk XOR swizzle (proven, 0 conflicts): lane (row,c) loads
// global chunk c^((row>>1)&3) into LDS chunk c; reader phys chunk = quad^((r15>>1)&3). ======

#define GEMM_COMMON_IDX                  \
  const int tid = threadIdx.x;           \
  const int lane = tid & 63;             \
  const int w = tid >> 6;                \
  const int r15 = lane & 15;             \
  const int quad = lane >> 4;            \
  const int pq = (quad ^ ((r15 >> 1) & 3)) * 8; \
  const int wm = (w >> 1) * 64;          \
  const int wn = (w & 1) * 64;

#define GEMM_ACC_INIT                    \
  floatx4 acc[4][4];                     \
  for (int i = 0; i < 4; ++i)            \
    for (int j = 0; j < 4; ++j) acc[i][j] = {0.f, 0.f, 0.f, 0.f};

// --- BK=32 single-buffer core (R0) — used by wprod ---
#define GEMM_STAGE_SETUP32(Abase, lda_, Bbase, ldb_)                          \
  const int srow = tid >> 2;                                                  \
  const int scg = (((tid & 3) ^ ((srow >> 1) & 3)) * 8);                      \
  const unsigned short* aG0 = (Abase) + (long long)srow * (lda_) + scg;       \
  const unsigned short* aG1 = aG0 + (long long)64 * (lda_);                   \
  const unsigned short* bG0 = (Bbase) + (long long)srow * (ldb_) + scg;       \
  const unsigned short* bG1 = bG0 + (long long)64 * (ldb_);                   \
  unsigned short* aL0 = As + w * 512;                                         \
  unsigned short* aL1 = As + w * 512 + 2048;                                  \
  unsigned short* bL0 = Bs + w * 512;                                         \
  unsigned short* bL1 = Bs + w * 512 + 2048;

#define GEMM_KLOOP32(Klen)                                                             \
  for (int k0 = 0; k0 < (Klen); k0 += 32) {                                            \
    gload16(aG0 + k0, aL0);                                                            \
    gload16(aG1 + k0, aL1);                                                            \
    gload16(bG0 + k0, bL0);                                                            \
    gload16(bG1 + k0, bL1);                                                            \
    __syncthreads();                                                                   \
    bf16x8 af[4], bfr[4];                                                              \
    for (int t = 0; t < 4; ++t) {                                                      \
      af[t] = *reinterpret_cast<const bf16x8*>(As + (wm + t * 16 + r15) * 32 + pq);    \
      bfr[t] = *reinterpret_cast<const bf16x8*>(Bs + (wn + t * 16 + r15) * 32 + pq);   \
    }                                                                                  \
    for (int mt = 0; mt < 4; ++mt)                                                     \
      for (int nt = 0; nt < 4; ++nt)                                                   \
        acc[mt][nt] =                                                                  \
            __builtin_amdgcn_mfma_f32_16x16x32_bf16(af[mt], bfr[nt], acc[mt][nt], 0, 0, 0); \
    __syncthreads();                                                                   \
  }

// --- BK=64 two-subtile core (R2, session-best total) — used by fused/scores/ctx ---
#define GEMM_STAGE_SETUP64(Abase, lda_, Bbase, ldb_)                          \
  const int srow = tid >> 2;                                                  \
  const int scg = (((tid & 3) ^ ((srow >> 1) & 3)) * 8);                      \
  const unsigned short* aG0 = (Abase) + (long long)srow * (lda_) + scg;       \
  const unsigned short* aG1 = aG0 + (long long)64 * (lda_);                   \
  const unsigned short* bG0 = (Bbase) + (long long)srow * (ldb_) + scg;       \
  const unsigned short* bG1 = bG0 + (long long)64 * (ldb_);

#define GEMM_KLOOP64(Klen)                                                               \
  for (int k0 = 0; k0 < (Klen); k0 += 64) {                                              \
    gload16(aG0 + k0, As[0] + w * 512);                                                  \
    gload16(aG1 + k0, As[0] + w * 512 + 2048);                                           \
    gload16(aG0 + k0 + 32, As[1] + w * 512);                                             \
    gload16(aG1 + k0 + 32, As[1] + w * 512 + 2048);                                      \
    gload16(bG0 + k0, Bs[0] + w * 512);                                                  \
    gload16(bG1 + k0, Bs[0] + w * 512 + 2048);                                           \
    gload16(bG0 + k0 + 32, Bs[1] + w * 512);                                             \
    gload16(bG1 + k0 + 32, Bs[1] + w * 512 + 2048);                                      \
    __syncthreads();                                                                     \
    for (int h = 0; h < 2; ++h) {                                                        \
      bf16x8 af[4], bfr[4];                                                              \
      for (int t = 0; t < 4; ++t) {                                                      \
        af[t] = *reinterpret_cast<const bf16x8*>(As[h] + (wm + t * 16 + r15) * 32 + pq); \
        bfr[t] = *reinterpret_cast<const bf16x8*>(Bs[h] + (wn + t * 16 + r15) * 32 + pq);\
      }                                                                                  \
      for (int mt = 0; mt < 4; ++mt)                                                     \
        for (int nt = 0; nt < 4; ++nt)                                                   \
          acc[mt][nt] =                                                                  \
              __builtin_amdgcn_mfma_f32_16x16x32_bf16(af[mt], bfr[nt], acc[mt][nt], 0, 0, 0); \
    }                                                                                    \
    __syncthreads();                                                                     \
  }

// ------- wprod: Mtb[i,j] = bf16(sum_c Wk[i,c]Wq[j,c] / 8), single pass, fp32 accum -------
// Blocks 0..63: 8x8 tiles, full K=1024 (castM kernel + fp32 partial traffic deleted).
// Blocks 64..127: t2/t3 bias rows (t2[i]=hsb_i·u + c/2, t3[j]=rhsb_j·v + c/2), zero-u exit.
__global__ __launch_bounds__(256) void wprod_kernel(
    const unsigned short* __restrict__ Wkb, const unsigned short* __restrict__ Wqb,
    unsigned short* __restrict__ Mtb, const unsigned short* __restrict__ hsb,
    const unsigned short* __restrict__ rhsb, const float* __restrict__ u,
    const float* __restrict__ v, const float* __restrict__ cbuf, float* __restrict__ t2,
    float* __restrict__ t3) {
  __shared__ __align__(16) unsigned short As[128 * 32];
  __shared__ __align__(16) unsigned short Bs[128 * 32];
  const int bid = blockIdx.x;
  if (bid < 64) {
    GEMM_COMMON_IDX
    const int bx = bid & 7;
    const int by = bid >> 3;
    const unsigned short* A = Wkb + (long long)by * 128 * D;
    const unsigned short* Bt = Wqb + (long long)bx * 128 * D;
    GEMM_STAGE_SETUP32(A, D, Bt, D)
    GEMM_ACC_INIT
    GEMM_KLOOP32(D)
    for (int mt = 0; mt < 4; ++mt)
      for (int nt = 0; nt < 4; ++nt) {
        const int mrow = by * 128 + wm + mt * 16 + quad * 4;
        const int nc = bx * 128 + wn + nt * 16 + r15;
        floatx4 vv = acc[mt][nt];
        for (int e = 0; e < 4; ++e)
          Mtb[(long long)(mrow + e) * 1024 + nc] = f2bf(vv[e] * 0.125f);
      }
  } else {
    const int tid = threadIdx.x;
    const bool isT2 = bid < 96;
    const int row = (isT2 ? (bid - 64) : (bid - 96)) * 256 + tid;  // 0..8191
    const float* vec = isT2 ? u : v;
    const unsigned short* mat = isT2 ? hsb : rhsb;
    float* out = isT2 ? t2 : t3;
    __shared__ int nz;
    if (tid == 0) nz = 0;
    __syncthreads();
    const float4* u4 = (const float4*)vec;
    float4 uu = u4[tid];
    if (uu.x != 0.f || uu.y != 0.f || uu.z != 0.f || uu.w != 0.f) nz = 1;
    __syncthreads();
    const float c2 = 0.5f * cbuf[0];
    if (!nz) {
      out[row] = c2;
      return;
    }
    const ushort4* r4 = (const ushort4*)(mat + (long long)row * 1024);
    float s = 0.f;
    for (int c4 = 0; c4 < 256; ++c4) {
      ushort4 h = r4[c4];
      s += bf2f(h.x) * vec[c4 * 4 + 0] + bf2f(h.y) * vec[c4 * 4 + 1] +
           bf2f(h.z) * vec[c4 * 4 + 2] + bf2f(h.w) * vec[c4 * 4 + 3];
    }
    out[row] = s + c2;
  }
}

// ---------------- fused GEMM: M=8192, N=2048: seg0 hsM = hsb·Mt^T, seg1 V-proj ----------------
// by-contiguous XCD swizzle: XCD k owns by in [8k,8k+8) x all 16 n-tiles -> per-XCD
// footprint ~2MB A + 4MB B (was: A-panels fetched ~8x, FETCH 135MB).
__global__ __launch_bounds__(256) void gemm_fused_kernel(
    const unsigned short* __restrict__ hsb, const unsigned short* __restrict__ rhsb,
    const unsigned short* __restrict__ Mtb, const unsigned short* __restrict__ WvT,
    const float* __restrict__ bv, unsigned short* __restrict__ hsMb,
    unsigned short* __restrict__ Vmt) {
  __shared__ __align__(16) unsigned short As[2][4096];
  __shared__ __align__(16) unsigned short Bs[2][4096];
  GEMM_COMMON_IDX
  const int bid = blockIdx.x;                   // 0..1023
  const int swz = (bid & 7) * 128 + (bid >> 3); // XCD-contiguous
  const int bx = swz & 15;
  const int by = swz >> 4;
  const int seg = bx >> 3;                      // 0=hsM 1=V
  const long long nloc = (long long)(bx & 7) * 128;
  const long long m0 = (long long)by * 128;
  const unsigned short* A = ((seg == 0) ? hsb : rhsb) + m0 * D;
  const unsigned short* Bt = ((seg == 0) ? Mtb : WvT) + nloc * D;

  GEMM_STAGE_SETUP64(A, D, Bt, D)
  GEMM_ACC_INIT
  GEMM_KLOOP64(D)

  for (int mt = 0; mt < 4; ++mt) {
    for (int nt = 0; nt < 4; ++nt) {
      const long long mrow = m0 + wm + mt * 16 + quad * 4;
      const long long nc = nloc + wn + nt * 16 + r15;
      floatx4 vv = acc[mt][nt];
      if (seg == 0) {
        for (int e = 0; e < 4; ++e) hsMb[(mrow + e) * D + nc] = f2bf(vv[e]);
      } else {
        const float bval = bv[nc];
        for (int e = 0; e < 4; ++e) {
          long long m = mrow + e;
          Vmt[(m >> 10) * (long long)(S * D) + nc * S + (m & 1023)] = f2bf(vv[e] + bval);
        }
      }
    }
  }
}

// ------- scores GEMM + fused mask/exp + partial row sums ---------
// sc = hsM·rhs (scale folded into Mt) + t2[row] + t3[col] + (1-mask)*-1e9; E = exp(sc).
// Batch-per-XCD swizzle: z = bid&7 -> XCD z reads only batch z's hsM+rhs slices (4MB).
__global__ __launch_bounds__(256) void gemm_scores_kernel(
    const unsigned short* __restrict__ hsMb, const unsigned short* __restrict__ rhsb,
    const float* __restrict__ mask, unsigned short* __restrict__ E, float* __restrict__ rowsumP,
    const float* __restrict__ t2, const float* __restrict__ t3) {
  __shared__ __align__(16) unsigned short As[2][4096];
  __shared__ __align__(16) unsigned short Bs[2][4096];
  GEMM_COMMON_IDX
  const int bid = blockIdx.x;  // 0..511
  const int z = bid & 7;       // batch == XCD
  const int r = bid >> 3;      // 0..63
  const int by = r >> 3;
  const int bx = r & 7;
  const long long m0 = (long long)by * 128;
  const long long n0 = (long long)bx * 128;
  const unsigned short* A = hsMb + (long long)z * S * D + m0 * D;
  const unsigned short* Bt = rhsb + (long long)z * S * D + n0 * D;

  GEMM_STAGE_SETUP64(A, D, Bt, D)
  GEMM_ACC_INIT
  GEMM_KLOOP64(D)

  const long long zE = (long long)z * S * 1024;
  float rowpart[4][4];
  for (int mt = 0; mt < 4; ++mt)
    for (int e = 0; e < 4; ++e) rowpart[mt][e] = 0.f;

  for (int mt = 0; mt < 4; ++mt) {
    for (int nt = 0; nt < 4; ++nt) {
      const long long mrow = m0 + wm + mt * 16 + quad * 4;
      const long long nc = n0 + wn + nt * 16 + r15;
      const float t3v = t3[z * 1024 + nc];
      floatx4 vv = acc[mt][nt];
      for (int e = 0; e < 4; ++e) {
        long long m = mrow + e;
        float mval = mask[zE + m * 1024 + nc];
        float sc = vv[e] + t2[z * 1024 + m] + t3v + (1.0f - mval) * -1e9f;
        float Ev = __expf(sc);
        E[zE + m * 1024 + nc] = f2bf(Ev);
        rowpart[mt][e] += Ev;
      }
    }
  }
  const int slot = (bx << 11) + ((wn >> 6) << 10);  // [ntile][half]
  for (int mt = 0; mt < 4; ++mt) {
    for (int e = 0; e < 4; ++e) {
      float s = rowpart[mt][e];
      s += __shfl_xor(s, 1, 64);
      s += __shfl_xor(s, 2, 64);
      s += __shfl_xor(s, 4, 64);
      s += __shfl_xor(s, 8, 64);
      if (r15 == 0) {
        int mloc = (int)(m0 + wm + mt * 16 + quad * 4 + e);
        rowsumP[(z << 14) + slot + mloc] = s;
      }
    }
  }
}

// ------- ctx GEMM: out = (E . Vmt^T) / rowsum, permuted store ---------
// Same batch-per-XCD swizzle: E[z] (2MB) re-read on the XCD that wrote it.
__global__ __launch_bounds__(256) void gemm_ctx_kernel(const unsigned short* __restrict__ E,
                                                       const unsigned short* __restrict__ Vmt,
                                                       const float* __restrict__ rowsumP,
                                                       float* __restrict__ out) {
  __shared__ __align__(16) unsigned short As[2][4096];
  __shared__ __align__(16) unsigned short Bs[2][4096];
  __shared__ float rsinv[128];
  GEMM_COMMON_IDX
  const int bid = blockIdx.x;  // 0..511
  const int z = bid & 7;
  const int r = bid >> 3;
  const int by = r >> 3;
  const int bx = r & 7;
  const long long m0 = (long long)by * 128;
  const long long n0 = (long long)bx * 128;
  const unsigned short* A = E + (long long)z * S * 1024 + m0 * 1024;
  const unsigned short* Bt = Vmt + (long long)z * S * D + n0 * D;

  if (tid < 128) {
    float s = 0.f;
    for (int t = 0; t < 16; ++t) s += rowsumP[(z << 14) + (t << 10) + (int)m0 + tid];
    rsinv[tid] = 1.0f / s;
  }

  GEMM_STAGE_SETUP64(A, 1024, Bt, D)
  GEMM_ACC_INIT
  GEMM_KLOOP64(1024)

  for (int mt = 0; mt < 4; ++mt) {
    for (int nt = 0; nt < 4; ++nt) {
      const int r0 = wm + mt * 16 + quad * 4;
      const long long ncol = n0 + wn + nt * 16 + r15;
      floatx4 vv = acc[mt][nt];
      for (int e = 0; e < 4; ++e) {
        long long m = m0 + r0 + e;
        float val = vv[e] * rsinv[r0 + e];
        out[(long long)z * S * D + (ncol >> 6) * (long long)(S * 64) + m * 64 + (ncol & 63)] =
            val;
      }
    }
  }
}

extern "C" void kernel_launch(void* const* d_in, const int* in_sizes, int n_in, void* d_out,
                              int out_size, void* d_ws, size_t ws_size, hipStream_t stream) {
  const float* hs = (const float*)d_in[0];
  const float* rhs = (const float*)d_in[1];
  const float* mask = (const float*)d_in[2];
  const float* Wq = (const float*)d_in[3];
  const float* bq = (const float*)d_in[4];
  const float* Wk = (const float*)d_in[5];
  const float* bk = (const float*)d_in[6];
  const float* Wv = (const float*)d_in[7];
  const float* bv = (const float*)d_in[8];
  float* out = (float*)d_out;
  char* ws = (char*)d_ws;
  const size_t MB = 1ull << 20;
  // layout (73 MB):
  // 0: WvT(2) | 2: Wqb(2) | 4: Wkb(2) | 6: Mtb(2) | 8: u/v/c/t2/t3/rowsumP (<1)
  // 9: hsb(16) [E overlays after fused] | 25: rhsb(16) | 41: hsMb(16) | 57: Vmt(16)
  unsigned short* WvT = (unsigned short*)(ws + 0 * MB);
  unsigned short* Wqb = (unsigned short*)(ws + 2 * MB);
  unsigned short* Wkb = (unsigned short*)(ws + 4 * MB);
  unsigned short* Mtb = (unsigned short*)(ws + 6 * MB);
  float* u = (float*)(ws + 8 * MB);
  float* v = (float*)(ws + 8 * MB + 4096);
  float* cbuf = (float*)(ws + 8 * MB + 8192);
  float* t2 = (float*)(ws + 8 * MB + 16384);
  float* t3 = (float*)(ws + 8 * MB + 49152);
  float* rowsumP = (float*)(ws + 8 * MB + 131072);
  unsigned short* hsb = (unsigned short*)(ws + 9 * MB);
  unsigned short* rhsb = (unsigned short*)(ws + 25 * MB);
  unsigned short* hsMb = (unsigned short*)(ws + 41 * MB);
  unsigned short* Vmt = (unsigned short*)(ws + 57 * MB);
  unsigned short* E = (unsigned short*)(ws + 9 * MB);

  const int n4 = NB * S * D / 4;  // 2M float4 per input
  prep_kernel<<<19465, 256, 0, stream>>>((const float4*)hs, (const float4*)rhs, (ushort4*)hsb,
                                         (ushort4*)rhsb, n4, Wq, Wk, Wv, WvT, (ushort4*)Wqb,
                                         (ushort4*)Wkb, bq, bk, u, v, cbuf);

  // Mt = Wk·Wq^T/8 (single pass, bf16 out) + t2/t3 bias rows
  wprod_kernel<<<128, 256, 0, stream>>>(Wkb, Wqb, Mtb, hsb, rhsb, u, v, cbuf, t2, t3);

  // fused: hsM projection (replaces Q-proj + K-proj) | V projection; XCD-swizzled
  gemm_fused_kernel<<<1024, 256, 0, stream>>>(hsb, rhsb, Mtb, WvT, bv, hsMb, Vmt);

  // E[b] = exp(hsM[b]·rhs[b]^T + t2 + t3 + mask) + partial row sums
  gemm_scores_kernel<<<512, 256, 0, stream>>>(hsMb, rhsb, mask, E, rowsumP, t2, t3);

  // ctx[b] = (E[b]·Vmt[b]^T)/rowsum, permuted fp32 store
  gemm_ctx_kernel<<<512, 256, 0, stream>>>(E, Vmt, rowsumP, out);
}

// Round 9
// 263.151 us; speedup vs baseline: 1.1770x; 1.1154x over previous
//
#include <hip/hip_runtime.h>
#include <stdint.h>

constexpr int S = 1024;
constexpr int D = 1024;
constexpr int NB = 8;

typedef __bf16 bf16x8 __attribute__((ext_vector_type(8)));
typedef float floatx4 __attribute__((ext_vector_type(4)));

#define AS1 __attribute__((address_space(1)))
#define AS3 __attribute__((address_space(3)))

__device__ __forceinline__ unsigned short f2bf(float f) {
  unsigned u = __builtin_bit_cast(unsigned, f);
  u += 0x7fffu + ((u >> 16) & 1u);  // RNE
  return (unsigned short)(u >> 16);
}

__device__ __forceinline__ ushort4 f2bf4(float4 w) {
  ushort4 o;
  o.x = f2bf(w.x); o.y = f2bf(w.y); o.z = f2bf(w.z); o.w = f2bf(w.w);
  return o;
}

__device__ __forceinline__ float bf2f(unsigned short x) {
  unsigned u = ((unsigned)x) << 16;
  return __builtin_bit_cast(float, u);
}

__device__ __forceinline__ void gload16(const void* g, void* l) {
  __builtin_amdgcn_global_load_lds((const AS1 unsigned int*)g, (AS3 unsigned int*)l, 16, 0, 0);
}

// ---------------- prep: casts (MLP=8) + Wv transpose + bias vectors u,v,c ----------------
// Algebra: scores = hs·(Wq Wk^T/8)·rhs^T + t2 + t3 (head-sum before softmax makes the
// score a FULL-D dot product -> the K-projection is algebraically redundant).
// R8 lesson: one-load-per-thread cast = latency-bound (1.4 TB/s); 8 independent loads/thread
// restores MLP. u/v: wave-per-row coalesced dot + zero-bias fast path.
__global__ __launch_bounds__(256) void prep_kernel(
    const float4* __restrict__ hs4, const float4* __restrict__ rhs4,
    ushort4* __restrict__ hsb4, ushort4* __restrict__ rhsb4,
    const float* __restrict__ Wq, const float* __restrict__ Wk, const float* __restrict__ Wv,
    unsigned short* __restrict__ WvT, ushort4* __restrict__ Wqb4, ushort4* __restrict__ Wkb4,
    const float* __restrict__ bq, const float* __restrict__ bk, float* __restrict__ u,
    float* __restrict__ v, float* __restrict__ cbuf) {
  __shared__ float tile[32][33];
  __shared__ float bsh[1024];
  __shared__ float sh[256];
  __shared__ int nz2;
  const int bid = blockIdx.x;
  const int tid = threadIdx.x;
  if (bid < 2048) {  // cast hs,rhs -> bf16: 8 independent float4 loads per thread
    const int base = bid * 256 + tid;  // 0..524287 ; n4 = 4*524288
    float4 a0 = hs4[base];
    float4 a1 = hs4[base + 524288];
    float4 a2 = hs4[base + 1048576];
    float4 a3 = hs4[base + 1572864];
    float4 b0 = rhs4[base];
    float4 b1 = rhs4[base + 524288];
    float4 b2 = rhs4[base + 1048576];
    float4 b3 = rhs4[base + 1572864];
    hsb4[base] = f2bf4(a0);
    hsb4[base + 524288] = f2bf4(a1);
    hsb4[base + 1048576] = f2bf4(a2);
    hsb4[base + 1572864] = f2bf4(a3);
    rhsb4[base] = f2bf4(b0);
    rhsb4[base + 524288] = f2bf4(b1);
    rhsb4[base + 1048576] = f2bf4(b2);
    rhsb4[base + 1572864] = f2bf4(b3);
  } else if (bid < 2304) {  // cast Wq,Wk -> bf16 (8 loads/thread)
    const int base = (bid - 2048) * 256 + tid;  // 0..65535 ; 262144 float4 each
    const float4* Wq4 = (const float4*)Wq;
    const float4* Wk4 = (const float4*)Wk;
    float4 a0 = Wq4[base];
    float4 a1 = Wq4[base + 65536];
    float4 a2 = Wq4[base + 131072];
    float4 a3 = Wq4[base + 196608];
    float4 b0 = Wk4[base];
    float4 b1 = Wk4[base + 65536];
    float4 b2 = Wk4[base + 131072];
    float4 b3 = Wk4[base + 196608];
    Wqb4[base] = f2bf4(a0);
    Wqb4[base + 65536] = f2bf4(a1);
    Wqb4[base + 131072] = f2bf4(a2);
    Wqb4[base + 196608] = f2bf4(a3);
    Wkb4[base] = f2bf4(b0);
    Wkb4[base + 65536] = f2bf4(b1);
    Wkb4[base + 131072] = f2bf4(b2);
    Wkb4[base + 196608] = f2bf4(b3);
  } else if (bid < 3328) {  // transpose-cast Wv -> WvT
    const int r = bid - 2304;      // 0..1023
    const int bx = (r & 31) * 32;  // n block
    const int by = (r >> 5) * 32;  // k block
    const int x = tid & 31;
    const int y0 = tid >> 5;
    for (int i = 0; i < 4; ++i) {
      int y = y0 + i * 8;
      tile[y][x] = Wv[(by + y) * D + bx + x];
    }
    __syncthreads();
    for (int i = 0; i < 4; ++i) {
      int y = y0 + i * 8;
      WvT[(long long)(bx + y) * D + by + x] = f2bf(tile[x][y]);
    }
  } else if (bid < 3336) {  // u = Wq@bk/8 (4 blocks), v = Wk@bq/8 (4 blocks); coalesced
    const bool isU = bid < 3332;
    const int blk = isU ? (bid - 3328) : (bid - 3332);
    const float* W = isU ? Wq : Wk;
    const float* bvec = isU ? bk : bq;
    float* outv = isU ? u : v;
    if (tid == 0) nz2 = 0;
    __syncthreads();
    float4 q = ((const float4*)bvec)[tid];
    bsh[tid * 4 + 0] = q.x;
    bsh[tid * 4 + 1] = q.y;
    bsh[tid * 4 + 2] = q.z;
    bsh[tid * 4 + 3] = q.w;
    if (q.x != 0.f || q.y != 0.f || q.z != 0.f || q.w != 0.f) nz2 = 1;
    __syncthreads();
    const int row0 = blk * 256;
    if (!nz2) {  // zero bias -> u/v rows are zero; skip the 4MB weight read
      outv[row0 + tid] = 0.f;
      return;
    }
    const int lane = tid & 63;
    const int wv = tid >> 6;
    for (int rr = 0; rr < 64; ++rr) {
      const int row = row0 + wv * 64 + rr;
      const float* rp = W + (long long)row * 1024;
      float s = 0.f;
#pragma unroll
      for (int k = 0; k < 16; ++k) s += rp[lane + 64 * k] * bsh[lane + 64 * k];
      s += __shfl_xor(s, 32, 64);
      s += __shfl_xor(s, 16, 64);
      s += __shfl_xor(s, 8, 64);
      s += __shfl_xor(s, 4, 64);
      s += __shfl_xor(s, 2, 64);
      s += __shfl_xor(s, 1, 64);
      if (lane == 0) outv[row] = 0.125f * s;
    }
  } else {  // c = bq·bk / 8
    float s = 0.f;
    for (int c = tid; c < 1024; c += 256) s += bq[c] * bk[c];
    sh[tid] = s;
    __syncthreads();
    for (int o = 128; o; o >>= 1) {
      if (tid < o) sh[tid] += sh[tid + o];
      __syncthreads();
    }
    if (tid == 0) cbuf[0] = 0.125f * sh[0];
  }
}

// ====== GEMM cores. Source-chunk XOR swizzle (proven, 0 conflicts): lane (row,c) loads
// global chunk c^((row>>1)&3) into LDS chunk c; reader phys chunk = quad^((r15>>1)&3). ======

#define GEMM_COMMON_IDX                  \
  const int tid = threadIdx.x;           \
  const int lane = tid & 63;             \
  const int w = tid >> 6;                \
  const int r15 = lane & 15;             \
  const int quad = lane >> 4;            \
  const int pq = (quad ^ ((r15 >> 1) & 3)) * 8; \
  const int wm = (w >> 1) * 64;          \
  const int wn = (w & 1) * 64;

#define GEMM_ACC_INIT                    \
  floatx4 acc[4][4];                     \
  for (int i = 0; i < 4; ++i)            \
    for (int j = 0; j < 4; ++j) acc[i][j] = {0.f, 0.f, 0.f, 0.f};

// --- BK=32 single-buffer core (R0) — used by wprod ---
#define GEMM_STAGE_SETUP32(Abase, lda_, Bbase, ldb_)                          \
  const int srow = tid >> 2;                                                  \
  const int scg = (((tid & 3) ^ ((srow >> 1) & 3)) * 8);                      \
  const unsigned short* aG0 = (Abase) + (long long)srow * (lda_) + scg;       \
  const unsigned short* aG1 = aG0 + (long long)64 * (lda_);                   \
  const unsigned short* bG0 = (Bbase) + (long long)srow * (ldb_) + scg;       \
  const unsigned short* bG1 = bG0 + (long long)64 * (ldb_);                   \
  unsigned short* aL0 = As + w * 512;                                         \
  unsigned short* aL1 = As + w * 512 + 2048;                                  \
  unsigned short* bL0 = Bs + w * 512;                                         \
  unsigned short* bL1 = Bs + w * 512 + 2048;

#define GEMM_KLOOP32(Klen)                                                             \
  for (int k0 = 0; k0 < (Klen); k0 += 32) {                                            \
    gload16(aG0 + k0, aL0);                                                            \
    gload16(aG1 + k0, aL1);                                                            \
    gload16(bG0 + k0, bL0);                                                            \
    gload16(bG1 + k0, bL1);                                                            \
    __syncthreads();                                                                   \
    bf16x8 af[4], bfr[4];                                                              \
    for (int t = 0; t < 4; ++t) {                                                      \
      af[t] = *reinterpret_cast<const bf16x8*>(As + (wm + t * 16 + r15) * 32 + pq);    \
      bfr[t] = *reinterpret_cast<const bf16x8*>(Bs + (wn + t * 16 + r15) * 32 + pq);   \
    }                                                                                  \
    for (int mt = 0; mt < 4; ++mt)                                                     \
      for (int nt = 0; nt < 4; ++nt)                                                   \
        acc[mt][nt] =                                                                  \
            __builtin_amdgcn_mfma_f32_16x16x32_bf16(af[mt], bfr[nt], acc[mt][nt], 0, 0, 0); \
    __syncthreads();                                                                   \
  }

// --- BK=64 two-subtile core (R2, session-best total) — used by fused/scores/ctx ---
#define GEMM_STAGE_SETUP64(Abase, lda_, Bbase, ldb_)                          \
  const int srow = tid >> 2;                                                  \
  const int scg = (((tid & 3) ^ ((srow >> 1) & 3)) * 8);                      \
  const unsigned short* aG0 = (Abase) + (long long)srow * (lda_) + scg;       \
  const unsigned short* aG1 = aG0 + (long long)64 * (lda_);                   \
  const unsigned short* bG0 = (Bbase) + (long long)srow * (ldb_) + scg;       \
  const unsigned short* bG1 = bG0 + (long long)64 * (ldb_);

#define GEMM_KLOOP64(Klen)                                                               \
  for (int k0 = 0; k0 < (Klen); k0 += 64) {                                              \
    gload16(aG0 + k0, As[0] + w * 512);                                                  \
    gload16(aG1 + k0, As[0] + w * 512 + 2048);                                           \
    gload16(aG0 + k0 + 32, As[1] + w * 512);                                             \
    gload16(aG1 + k0 + 32, As[1] + w * 512 + 2048);                                      \
    gload16(bG0 + k0, Bs[0] + w * 512);                                                  \
    gload16(bG1 + k0, Bs[0] + w * 512 + 2048);                                           \
    gload16(bG0 + k0 + 32, Bs[1] + w * 512);                                             \
    gload16(bG1 + k0 + 32, Bs[1] + w * 512 + 2048);                                      \
    __syncthreads();                                                                     \
    for (int h = 0; h < 2; ++h) {                                                        \
      bf16x8 af[4], bfr[4];                                                              \
      for (int t = 0; t < 4; ++t) {                                                      \
        af[t] = *reinterpret_cast<const bf16x8*>(As[h] + (wm + t * 16 + r15) * 32 + pq); \
        bfr[t] = *reinterpret_cast<const bf16x8*>(Bs[h] + (wn + t * 16 + r15) * 32 + pq);\
      }                                                                                  \
      for (int mt = 0; mt < 4; ++mt)                                                     \
        for (int nt = 0; nt < 4; ++nt)                                                   \
          acc[mt][nt] =                                                                  \
              __builtin_amdgcn_mfma_f32_16x16x32_bf16(af[mt], bfr[nt], acc[mt][nt], 0, 0, 0); \
    }                                                                                    \
    __syncthreads();                                                                     \
  }

// ------- wprod: Mt partials (split-K x4, 256 blocks — R7-proven parallelism) -------
// Blocks 0..255: Mtf[kc] += Wk·Wq^T/8 over K-chunk kc*256. Blocks 256..319: t2/t3 rows
// (t2[i]=hsb_i·u + c/2, t3[j]=rhsb_j·v + c/2) with all-zero-u fast exit.
__global__ __launch_bounds__(256) void wprod_kernel(
    const unsigned short* __restrict__ Wkb, const unsigned short* __restrict__ Wqb,
    float* __restrict__ Mtf, const unsigned short* __restrict__ hsb,
    const unsigned short* __restrict__ rhsb, const float* __restrict__ u,
    const float* __restrict__ v, const float* __restrict__ cbuf, float* __restrict__ t2,
    float* __restrict__ t3) {
  __shared__ __align__(16) unsigned short As[128 * 32];
  __shared__ __align__(16) unsigned short Bs[128 * 32];
  const int bid = blockIdx.x;
  if (bid < 256) {
    GEMM_COMMON_IDX
    const int tilei = bid & 63;
    const int kc = bid >> 6;  // k-chunk 0..3
    const int bx = tilei & 7;
    const int by = tilei >> 3;
    const unsigned short* A = Wkb + (long long)by * 128 * D + kc * 256;
    const unsigned short* Bt = Wqb + (long long)bx * 128 * D + kc * 256;
    GEMM_STAGE_SETUP32(A, D, Bt, D)
    GEMM_ACC_INIT
    GEMM_KLOOP32(256)
    float* dst = Mtf + ((long long)kc << 20);
    for (int mt = 0; mt < 4; ++mt)
      for (int nt = 0; nt < 4; ++nt) {
        const int mrow = by * 128 + wm + mt * 16 + quad * 4;
        const int nc = bx * 128 + wn + nt * 16 + r15;
        floatx4 vv = acc[mt][nt];
        for (int e = 0; e < 4; ++e) dst[(long long)(mrow + e) * 1024 + nc] = vv[e] * 0.125f;
      }
  } else {
    const int tid = threadIdx.x;
    const bool isT2 = bid < 288;
    const int row = (isT2 ? (bid - 256) : (bid - 288)) * 256 + tid;  // 0..8191
    const float* vec = isT2 ? u : v;
    const unsigned short* mat = isT2 ? hsb : rhsb;
    float* out = isT2 ? t2 : t3;
    __shared__ int nz;
    if (tid == 0) nz = 0;
    __syncthreads();
    const float4* u4 = (const float4*)vec;
    float4 uu = u4[tid];
    if (uu.x != 0.f || uu.y != 0.f || uu.z != 0.f || uu.w != 0.f) nz = 1;
    __syncthreads();
    const float c2 = 0.5f * cbuf[0];
    if (!nz) {
      out[row] = c2;
      return;
    }
    const ushort4* r4 = (const ushort4*)(mat + (long long)row * 1024);
    float s = 0.f;
    for (int c4 = 0; c4 < 256; ++c4) {
      ushort4 h = r4[c4];
      s += bf2f(h.x) * vec[c4 * 4 + 0] + bf2f(h.y) * vec[c4 * 4 + 1] +
           bf2f(h.z) * vec[c4 * 4 + 2] + bf2f(h.w) * vec[c4 * 4 + 3];
    }
    out[row] = s + c2;
  }
}

// ------- castM: Mtb = bf16(sum of 4 fp32 K-partials) -------
__global__ __launch_bounds__(256) void castM_kernel(const float4* __restrict__ Mtf4,
                                                    ushort4* __restrict__ Mtb4) {
  const int j = blockIdx.x * 256 + threadIdx.x;  // 0..262143
  float4 a = Mtf4[j];
  float4 b = Mtf4[j + 262144];
  float4 c = Mtf4[j + 524288];
  float4 d = Mtf4[j + 786432];
  ushort4 o;
  o.x = f2bf(a.x + b.x + c.x + d.x);
  o.y = f2bf(a.y + b.y + c.y + d.y);
  o.z = f2bf(a.z + b.z + c.z + d.z);
  o.w = f2bf(a.w + b.w + c.w + d.w);
  Mtb4[j] = o;
}

// ---------------- fused GEMM: M=8192, N=2048: seg0 hsM = hsb·Mt^T, seg1 V-proj ----------------
// by-contiguous XCD swizzle: XCD k owns by in [8k,8k+8) x all 16 n-tiles.
__global__ __launch_bounds__(256) void gemm_fused_kernel(
    const unsigned short* __restrict__ hsb, const unsigned short* __restrict__ rhsb,
    const unsigned short* __restrict__ Mtb, const unsigned short* __restrict__ WvT,
    const float* __restrict__ bv, unsigned short* __restrict__ hsMb,
    unsigned short* __restrict__ Vmt) {
  __shared__ __align__(16) unsigned short As[2][4096];
  __shared__ __align__(16) unsigned short Bs[2][4096];
  GEMM_COMMON_IDX
  const int bid = blockIdx.x;                   // 0..1023
  const int swz = (bid & 7) * 128 + (bid >> 3); // XCD-contiguous
  const int bx = swz & 15;
  const int by = swz >> 4;
  const int seg = bx >> 3;                      // 0=hsM 1=V
  const long long nloc = (long long)(bx & 7) * 128;
  const long long m0 = (long long)by * 128;
  const unsigned short* A = ((seg == 0) ? hsb : rhsb) + m0 * D;
  const unsigned short* Bt = ((seg == 0) ? Mtb : WvT) + nloc * D;

  GEMM_STAGE_SETUP64(A, D, Bt, D)
  GEMM_ACC_INIT
  GEMM_KLOOP64(D)

  for (int mt = 0; mt < 4; ++mt) {
    for (int nt = 0; nt < 4; ++nt) {
      const long long mrow = m0 + wm + mt * 16 + quad * 4;
      const long long nc = nloc + wn + nt * 16 + r15;
      floatx4 vv = acc[mt][nt];
      if (seg == 0) {
        for (int e = 0; e < 4; ++e) hsMb[(mrow + e) * D + nc] = f2bf(vv[e]);
      } else {
        const float bval = bv[nc];
        for (int e = 0; e < 4; ++e) {
          long long m = mrow + e;
          Vmt[(m >> 10) * (long long)(S * D) + nc * S + (m & 1023)] = f2bf(vv[e] + bval);
        }
      }
    }
  }
}

// ------- scores GEMM + fused mask/exp + partial row sums ---------
// sc = hsM·rhs (scale folded into Mt) + t2[row] + t3[col] + (1-mask)*-1e9; E = exp(sc).
// Batch-per-XCD swizzle: z = bid&7.
__global__ __launch_bounds__(256) void gemm_scores_kernel(
    const unsigned short* __restrict__ hsMb, const unsigned short* __restrict__ rhsb,
    const float* __restrict__ mask, unsigned short* __restrict__ E, float* __restrict__ rowsumP,
    const float* __restrict__ t2, const float* __restrict__ t3) {
  __shared__ __align__(16) unsigned short As[2][4096];
  __shared__ __align__(16) unsigned short Bs[2][4096];
  GEMM_COMMON_IDX
  const int bid = blockIdx.x;  // 0..511
  const int z = bid & 7;       // batch == XCD
  const int r = bid >> 3;      // 0..63
  const int by = r >> 3;
  const int bx = r & 7;
  const long long m0 = (long long)by * 128;
  const long long n0 = (long long)bx * 128;
  const unsigned short* A = hsMb + (long long)z * S * D + m0 * D;
  const unsigned short* Bt = rhsb + (long long)z * S * D + n0 * D;

  GEMM_STAGE_SETUP64(A, D, Bt, D)
  GEMM_ACC_INIT
  GEMM_KLOOP64(D)

  const long long zE = (long long)z * S * 1024;
  float rowpart[4][4];
  for (int mt = 0; mt < 4; ++mt)
    for (int e = 0; e < 4; ++e) rowpart[mt][e] = 0.f;

  for (int mt = 0; mt < 4; ++mt) {
    for (int nt = 0; nt < 4; ++nt) {
      const long long mrow = m0 + wm + mt * 16 + quad * 4;
      const long long nc = n0 + wn + nt * 16 + r15;
      const float t3v = t3[z * 1024 + nc];
      floatx4 vv = acc[mt][nt];
      for (int e = 0; e < 4; ++e) {
        long long m = mrow + e;
        float mval = mask[zE + m * 1024 + nc];
        float sc = vv[e] + t2[z * 1024 + m] + t3v + (1.0f - mval) * -1e9f;
        float Ev = __expf(sc);
        E[zE + m * 1024 + nc] = f2bf(Ev);
        rowpart[mt][e] += Ev;
      }
    }
  }
  const int slot = (bx << 11) + ((wn >> 6) << 10);  // [ntile][half]
  for (int mt = 0; mt < 4; ++mt) {
    for (int e = 0; e < 4; ++e) {
      float s = rowpart[mt][e];
      s += __shfl_xor(s, 1, 64);
      s += __shfl_xor(s, 2, 64);
      s += __shfl_xor(s, 4, 64);
      s += __shfl_xor(s, 8, 64);
      if (r15 == 0) {
        int mloc = (int)(m0 + wm + mt * 16 + quad * 4 + e);
        rowsumP[(z << 14) + slot + mloc] = s;
      }
    }
  }
}

// ------- ctx GEMM: out = (E . Vmt^T) / rowsum, permuted store ---------
__global__ __launch_bounds__(256) void gemm_ctx_kernel(const unsigned short* __restrict__ E,
                                                       const unsigned short* __restrict__ Vmt,
                                                       const float* __restrict__ rowsumP,
                                                       float* __restrict__ out) {
  __shared__ __align__(16) unsigned short As[2][4096];
  __shared__ __align__(16) unsigned short Bs[2][4096];
  __shared__ float rsinv[128];
  GEMM_COMMON_IDX
  const int bid = blockIdx.x;  // 0..511
  const int z = bid & 7;
  const int r = bid >> 3;
  const int by = r >> 3;
  const int bx = r & 7;
  const long long m0 = (long long)by * 128;
  const long long n0 = (long long)bx * 128;
  const unsigned short* A = E + (long long)z * S * 1024 + m0 * 1024;
  const unsigned short* Bt = Vmt + (long long)z * S * D + n0 * D;

  if (tid < 128) {
    float s = 0.f;
    for (int t = 0; t < 16; ++t) s += rowsumP[(z << 14) + (t << 10) + (int)m0 + tid];
    rsinv[tid] = 1.0f / s;
  }

  GEMM_STAGE_SETUP64(A, 1024, Bt, D)
  GEMM_ACC_INIT
  GEMM_KLOOP64(1024)

  for (int mt = 0; mt < 4; ++mt) {
    for (int nt = 0; nt < 4; ++nt) {
      const int r0 = wm + mt * 16 + quad * 4;
      const long long ncol = n0 + wn + nt * 16 + r15;
      floatx4 vv = acc[mt][nt];
      for (int e = 0; e < 4; ++e) {
        long long m = m0 + r0 + e;
        float val = vv[e] * rsinv[r0 + e];
        out[(long long)z * S * D + (ncol >> 6) * (long long)(S * 64) + m * 64 + (ncol & 63)] =
            val;
      }
    }
  }
}

extern "C" void kernel_launch(void* const* d_in, const int* in_sizes, int n_in, void* d_out,
                              int out_size, void* d_ws, size_t ws_size, hipStream_t stream) {
  const float* hs = (const float*)d_in[0];
  const float* rhs = (const float*)d_in[1];
  const float* mask = (const float*)d_in[2];
  const float* Wq = (const float*)d_in[3];
  const float* bq = (const float*)d_in[4];
  const float* Wk = (const float*)d_in[5];
  const float* bk = (const float*)d_in[6];
  const float* Wv = (const float*)d_in[7];
  const float* bv = (const float*)d_in[8];
  float* out = (float*)d_out;
  char* ws = (char*)d_ws;
  const size_t MB = 1ull << 20;
  // layout (73 MB):
  // 0: WvT(2) | 2: Wqb(2) | 4: Wkb(2) | 6: Mtb(2) | 8: u/v/c/t2/t3/rowsumP (<1)
  // 9: hsb(16) [E overlays after fused] | 25: rhsb(16)
  // 41: hsMb(16) [Mtf fp32 overlays BEFORE fused] | 57: Vmt(16)
  unsigned short* WvT = (unsigned short*)(ws + 0 * MB);
  unsigned short* Wqb = (unsigned short*)(ws + 2 * MB);
  unsigned short* Wkb = (unsigned short*)(ws + 4 * MB);
  unsigned short* Mtb = (unsigned short*)(ws + 6 * MB);
  float* u = (float*)(ws + 8 * MB);
  float* v = (float*)(ws + 8 * MB + 4096);
  float* cbuf = (float*)(ws + 8 * MB + 8192);
  float* t2 = (float*)(ws + 8 * MB + 16384);
  float* t3 = (float*)(ws + 8 * MB + 49152);
  float* rowsumP = (float*)(ws + 8 * MB + 131072);
  unsigned short* hsb = (unsigned short*)(ws + 9 * MB);
  unsigned short* rhsb = (unsigned short*)(ws + 25 * MB);
  unsigned short* hsMb = (unsigned short*)(ws + 41 * MB);
  float* Mtf = (float*)(ws + 41 * MB);
  unsigned short* Vmt = (unsigned short*)(ws + 57 * MB);
  unsigned short* E = (unsigned short*)(ws + 9 * MB);

  prep_kernel<<<3337, 256, 0, stream>>>((const float4*)hs, (const float4*)rhs, (ushort4*)hsb,
                                        (ushort4*)rhsb, Wq, Wk, Wv, WvT, (ushort4*)Wqb,
                                        (ushort4*)Wkb, bq, bk, u, v, cbuf);

  // Mt = Wk·Wq^T/8 (split-K x4 fp32 partials, 256 blocks) + t2/t3 bias rows
  wprod_kernel<<<320, 256, 0, stream>>>(Wkb, Wqb, Mtf, hsb, rhsb, u, v, cbuf, t2, t3);
  castM_kernel<<<1024, 256, 0, stream>>>((const float4*)Mtf, (ushort4*)Mtb);

  // fused: hsM projection (replaces Q-proj + K-proj) | V projection; XCD-swizzled
  gemm_fused_kernel<<<1024, 256, 0, stream>>>(hsb, rhsb, Mtb, WvT, bv, hsMb, Vmt);

  // E[b] = exp(hsM[b]·rhs[b]^T + t2 + t3 + mask) + partial row sums
  gemm_scores_kernel<<<512, 256, 0, stream>>>(hsMb, rhsb, mask, E, rowsumP, t2, t3);

  // ctx[b] = (E[b]·Vmt[b]^T)/rowsum, permuted fp32 store
  gemm_ctx_kernel<<<512, 256, 0, stream>>>(E, Vmt, rowsumP, out);
}